// Round 13
// baseline (194.852 us; speedup 1.0000x reference)
//
#include <hip/hip_runtime.h>
#include <hip/hip_bf16.h>

#define S_LEN   2048
#define D_MODEL 1024
#define N_HEADS 16
#define N_GROUPS 4
#define D_K     64
#define KV_DIM  (N_GROUPS * D_K)   // 256

typedef __hip_bfloat16 bf16;
typedef unsigned short u16;
typedef __attribute__((ext_vector_type(8))) short bfrag;   // 8 bf16 = 4 VGPR
typedef __attribute__((ext_vector_type(4))) float ffrag;   // 4 fp32 acc

__device__ __forceinline__ float b2f(u16 u) {
    return __uint_as_float(((unsigned)u) << 16);
}
__device__ __forceinline__ u16 f2bu(float f) {
    bf16 h = __float2bfloat16(f);
    return __builtin_bit_cast(u16, h);
}

// ---- DPP 16-lane rotate reductions (VALU pipe, not LDS) ----
template <int CTRL>
__device__ __forceinline__ float dpp_f(float x) {
    return __builtin_bit_cast(float,
        __builtin_amdgcn_update_dpp(0, __builtin_bit_cast(int, x), CTRL, 0xF, 0xF, false));
}
__device__ __forceinline__ float rmax16(float x) {
    x = fmaxf(x, dpp_f<0x128>(x));   // row_ror:8
    x = fmaxf(x, dpp_f<0x124>(x));   // row_ror:4
    x = fmaxf(x, dpp_f<0x122>(x));   // row_ror:2
    x = fmaxf(x, dpp_f<0x121>(x));   // row_ror:1
    return x;
}
__device__ __forceinline__ float rsum16(float x) {
    x += dpp_f<0x128>(x);
    x += dpp_f<0x124>(x);
    x += dpp_f<0x122>(x);
    x += dpp_f<0x121>(x);
    return x;
}

// ---------------- per-input dtype probe (established: all fp32) ----------------
__global__ void probe5_kernel(const u16* __restrict__ p0, const u16* __restrict__ p1,
                              const u16* __restrict__ p2, const u16* __restrict__ p3,
                              const u16* __restrict__ p4, int* __restrict__ mode) {
    if (threadIdx.x == 0 && blockIdx.x == 0) {
        const u16* ps[5] = {p0, p1, p2, p3, p4};
        for (int t = 0; t < 5; t++) {
            int extreme = 0;
            for (int i = 0; i < 128; i++) {
                int e = (ps[t][i] >> 7) & 0xFF;
                if (e < 100 || e > 140) extreme++;
            }
            mode[t] = (extreme > 16) ? 1 : 0;
        }
    }
}

// ---------------- RoPE (fp32 math, bf16 out) ----------------
__global__ __launch_bounds__(512)
void rope_kernel(const void* __restrict__ Xin, u16* __restrict__ Xr,
                 const int* __restrict__ mode) {
    int i = blockIdx.x;
    int j = threadIdx.x;
    int md = mode[0];
    float freq = powf(10000.0f, -(float)j * (1.0f / 512.0f));
    float ang  = (float)i * freq;
    float sv, cv;
    sincosf(ang, &sv, &cv);
    int base = i * D_MODEL;
    float xe, xo;
    if (md) {
        float2 xv = *(const float2*)&((const float*)Xin)[base + 2 * j];
        xe = xv.x; xo = xv.y;
    } else {
        ushort2 xv = *(const ushort2*)&((const u16*)Xin)[base + 2 * j];
        xe = b2f(xv.x); xo = b2f(xv.y);
    }
    Xr[base + j]       = f2bu(xe * cv - xo * sv);
    Xr[base + 512 + j] = f2bu(xe * sv + xo * cv);
}

// ---- helper: stage one B-panel row-chunk from fp32/bf16 weights ----
__device__ __forceinline__ void stageB(u16* dst, const void* Bv, size_t off, int md) {
    if (md) {
        const float* Bf = (const float*)Bv;
        float4 b0 = *(const float4*)&Bf[off];
        float4 b1 = *(const float4*)&Bf[off + 4];
        u16 t[8] = {f2bu(b0.x), f2bu(b0.y), f2bu(b0.z), f2bu(b0.w),
                    f2bu(b1.x), f2bu(b1.y), f2bu(b1.z), f2bu(b1.w)};
        *(uint4*)dst = *(const uint4*)t;
    } else {
        *(uint4*)dst = *(const uint4*)&((const u16*)Bv)[off];
    }
}

// ---------------- fused QKV projection (MFMA) ----------
__global__ __launch_bounds__(256)
void qkv_mfma(const u16* __restrict__ Xr, const void* __restrict__ Wq,
              const void* __restrict__ Wk, const void* __restrict__ Wv,
              u16* __restrict__ Qm, u16* __restrict__ Km, u16* __restrict__ Vm,
              const int* __restrict__ mode) {
    __shared__ u16 As[128][36];
    __shared__ u16 Bs[64][36];
    const int tid = threadIdx.x;
    const int w = tid >> 6, lane = tid & 63, quad = lane >> 4, lcol = lane & 15;
    const int m0 = blockIdx.y * 128;
    const int n0 = blockIdx.x * 64;

    const void* Bv; int nb, md;
    if (n0 < 1024)       { Bv = Wq; nb = n0;        md = mode[1]; }
    else if (n0 < 1280)  { Bv = Wk; nb = n0 - 1024; md = mode[2]; }
    else                 { Bv = Wv; nb = n0 - 1280; md = mode[3]; }

    ffrag acc[2][4];
    #pragma unroll
    for (int rf = 0; rf < 2; rf++)
        #pragma unroll
        for (int ct = 0; ct < 4; ct++) acc[rf][ct] = (ffrag)0.0f;

    const int arow = tid >> 2, akc = tid & 3;
    for (int k0 = 0; k0 < D_MODEL; k0 += 32) {
        *(uint4*)&As[arow][akc * 8] =
            *(const uint4*)&Xr[(size_t)(m0 + arow) * D_MODEL + k0 + akc * 8];
        *(uint4*)&As[arow + 64][akc * 8] =
            *(const uint4*)&Xr[(size_t)(m0 + arow + 64) * D_MODEL + k0 + akc * 8];
        stageB(&Bs[arow][akc * 8], Bv, (size_t)(nb + arow) * D_MODEL + k0 + akc * 8, md);
        __syncthreads();
        const bfrag a0 = *(const bfrag*)&As[w * 32 + lcol][quad * 8];
        const bfrag a1 = *(const bfrag*)&As[w * 32 + 16 + lcol][quad * 8];
        #pragma unroll
        for (int ct = 0; ct < 4; ct++) {
            const bfrag b = *(const bfrag*)&Bs[ct * 16 + lcol][quad * 8];
            acc[0][ct] = __builtin_amdgcn_mfma_f32_16x16x32_bf16(a0, b, acc[0][ct], 0, 0, 0);
            acc[1][ct] = __builtin_amdgcn_mfma_f32_16x16x32_bf16(a1, b, acc[1][ct], 0, 0, 0);
        }
        __syncthreads();
    }

    u16* Cp; int ldc, nc;
    if (n0 < 1024)      { Cp = Qm; ldc = 1024; nc = n0; }
    else if (n0 < 1280) { Cp = Km; ldc = 256;  nc = n0 - 1024; }
    else                { Cp = Vm; ldc = 256;  nc = n0 - 1280; }
    #pragma unroll
    for (int rf = 0; rf < 2; rf++)
        #pragma unroll
        for (int ct = 0; ct < 4; ct++)
            #pragma unroll
            for (int r = 0; r < 4; r++) {
                int row = m0 + w * 32 + rf * 16 + quad * 4 + r;
                Cp[(size_t)row * ldc + nc + ct * 16 + lcol] = f2bu(acc[rf][ct][r]);
            }
}

// ---------------- O projection: C fp32 = A(bf16) B^T ----------------
__global__ __launch_bounds__(256)
void oproj_mfma(const u16* __restrict__ A, const void* __restrict__ B,
                float* __restrict__ C, const int* __restrict__ mode) {
    __shared__ u16 As[128][36];
    __shared__ u16 Bs[64][36];
    const int tid = threadIdx.x;
    const int w = tid >> 6, lane = tid & 63, quad = lane >> 4, lcol = lane & 15;
    const int m0 = blockIdx.y * 128;
    const int n0 = blockIdx.x * 64;
    const int md = mode[4];

    ffrag acc[2][4];
    #pragma unroll
    for (int rf = 0; rf < 2; rf++)
        #pragma unroll
        for (int ct = 0; ct < 4; ct++) acc[rf][ct] = (ffrag)0.0f;

    const int arow = tid >> 2, akc = tid & 3;
    for (int k0 = 0; k0 < D_MODEL; k0 += 32) {
        *(uint4*)&As[arow][akc * 8] =
            *(const uint4*)&A[(size_t)(m0 + arow) * D_MODEL + k0 + akc * 8];
        *(uint4*)&As[arow + 64][akc * 8] =
            *(const uint4*)&A[(size_t)(m0 + arow + 64) * D_MODEL + k0 + akc * 8];
        stageB(&Bs[arow][akc * 8], B, (size_t)(n0 + arow) * D_MODEL + k0 + akc * 8, md);
        __syncthreads();
        const bfrag a0 = *(const bfrag*)&As[w * 32 + lcol][quad * 8];
        const bfrag a1 = *(const bfrag*)&As[w * 32 + 16 + lcol][quad * 8];
        #pragma unroll
        for (int ct = 0; ct < 4; ct++) {
            const bfrag b = *(const bfrag*)&Bs[ct * 16 + lcol][quad * 8];
            acc[0][ct] = __builtin_amdgcn_mfma_f32_16x16x32_bf16(a0, b, acc[0][ct], 0, 0, 0);
            acc[1][ct] = __builtin_amdgcn_mfma_f32_16x16x32_bf16(a1, b, acc[1][ct], 0, 0, 0);
        }
        __syncthreads();
    }

    #pragma unroll
    for (int rf = 0; rf < 2; rf++)
        #pragma unroll
        for (int ct = 0; ct < 4; ct++)
            #pragma unroll
            for (int r = 0; r < 4; r++) {
                int row = m0 + w * 32 + rf * 16 + quad * 4 + r;
                C[(size_t)row * D_MODEL + n0 + ct * 16 + lcol] = acc[rf][ct][r];
            }
}

// ---------------- V transpose: Vm[key][256dim] -> Vt[256dim][key] ----------------
__global__ __launch_bounds__(256)
void vt_kernel(const u16* __restrict__ Vm, u16* __restrict__ Vt) {
    __shared__ u16 T[64][72];
    const int k0 = blockIdx.x * 64;
    const int d0 = blockIdx.y * 64;
    const int tid = threadIdx.x;
    #pragma unroll
    for (int rep = 0; rep < 2; rep++) {
        int idx = tid + rep * 256;
        int row = idx >> 3, c8 = idx & 7;
        *(uint4*)&T[row][c8 * 8] =
            *(const uint4*)&Vm[(size_t)(k0 + row) * KV_DIM + d0 + c8 * 8];
    }
    __syncthreads();
    #pragma unroll
    for (int rep = 0; rep < 2; rep++) {
        int idx = tid + rep * 256;
        int drow = idx >> 3, kc8 = idx & 7;
        u16 tmp[8];
        #pragma unroll
        for (int j = 0; j < 8; j++) tmp[j] = T[kc8 * 8 + j][drow];
        *(uint4*)&Vt[(size_t)(d0 + drow) * S_LEN + k0 + kc8 * 8] = *(const uint4*)tmp;
    }
}

// ---------------- split-K MFMA flash attention partials ----------------
// Block = 128 queries (4 waves x 32) x one chunk of up to 8 key-tiles x head.
// cidx logical chunk: i<4:1 chunk, i<8:2, i<12:3, i<16:4 (total 40). Launched
// in reverse (longest chunks first). bf16 partials + (m,l).
__global__ __launch_bounds__(256)
void attn_part(const u16* __restrict__ Q, const u16* __restrict__ K,
               const u16* __restrict__ Vt, u16* __restrict__ OpH,
               float2* __restrict__ ml2) {
    const int bid = blockIdx.x;
    const int cidx = 39 - (bid >> 4);          // longest-first
    const int h = bid & 15;
    const int g = h >> 2;

    int i, c;
    if (cidx < 4)       { i = cidx; c = 0; }
    else if (cidx < 12) { i = 4 + ((cidx - 4) >> 1); c = (cidx - 4) & 1; }
    else if (cidx < 24) { int q3 = (cidx - 12) / 3; i = 8 + q3; c = (cidx - 12) - 3 * q3; }
    else                { i = 12 + ((cidx - 24) >> 2); c = (cidx - 24) & 3; }

    const int q0 = i * 128;
    const int tile0 = c * 8;
    const int nt = min(2 * i + 2, tile0 + 8) - tile0;

    const int tid  = threadIdx.x;
    const int w    = tid >> 6;
    const int lane = tid & 63;
    const int quad = lane >> 4;
    const int lcol = lane & 15;

    __shared__ u16 Ks[64][72];       // [key][dim]
    __shared__ u16 Vs[64][72];       // [dim][key]  (from Vt)
    __shared__ u16 Ps[4][32][72];    // per-wave P

    // Q fragments: wave w rows q0 + w*32 + rf*16 + lcol
    bfrag qa[2][2];
    #pragma unroll
    for (int rf = 0; rf < 2; rf++)
        #pragma unroll
        for (int kc = 0; kc < 2; kc++)
            qa[rf][kc] = *(const bfrag*)&Q[(size_t)(q0 + w * 32 + rf * 16 + lcol) * D_MODEL
                                           + h * 64 + kc * 32 + quad * 8];

    ffrag oacc[2][4];
    #pragma unroll
    for (int rf = 0; rf < 2; rf++)
        #pragma unroll
        for (int ct = 0; ct < 4; ct++) oacc[rf][ct] = (ffrag)0.0f;
    float m_run[2][4], l_run[2][4];
    #pragma unroll
    for (int rf = 0; rf < 2; rf++)
        #pragma unroll
        for (int r = 0; r < 4; r++) { m_run[rf][r] = -1e30f; l_run[rf][r] = 0.0f; }

    // staging indices: idx = tid + rep*256 in [0,512): row = idx>>3, c8 = idx&7
    const int srow0 = tid >> 3,          sc80 = tid & 7;
    const int srow1 = (tid + 256) >> 3,  sc81 = (tid + 256) & 7;

    int j0 = tile0 * 64;
    uint4 kp0 = *(const uint4*)&K[(size_t)(j0 + srow0) * KV_DIM + g * 64 + sc80 * 8];
    uint4 kp1 = *(const uint4*)&K[(size_t)(j0 + srow1) * KV_DIM + g * 64 + sc81 * 8];
    uint4 vp0 = *(const uint4*)&Vt[(size_t)(g * 64 + srow0) * S_LEN + j0 + sc80 * 8];
    uint4 vp1 = *(const uint4*)&Vt[(size_t)(g * 64 + srow1) * S_LEN + j0 + sc81 * 8];

    for (int tt = 0; tt < nt; tt++) {
        j0 = (tile0 + tt) * 64;

        *(uint4*)&Ks[srow0][sc80 * 8] = kp0;
        *(uint4*)&Ks[srow1][sc81 * 8] = kp1;
        *(uint4*)&Vs[srow0][sc80 * 8] = vp0;
        *(uint4*)&Vs[srow1][sc81 * 8] = vp1;
        __syncthreads();

        if (tt + 1 < nt) {
            const int j0n = j0 + 64;
            kp0 = *(const uint4*)&K[(size_t)(j0n + srow0) * KV_DIM + g * 64 + sc80 * 8];
            kp1 = *(const uint4*)&K[(size_t)(j0n + srow1) * KV_DIM + g * 64 + sc81 * 8];
            vp0 = *(const uint4*)&Vt[(size_t)(g * 64 + srow0) * S_LEN + j0n + sc80 * 8];
            vp1 = *(const uint4*)&Vt[(size_t)(g * 64 + srow1) * S_LEN + j0n + sc81 * 8];
        }

        // ---- S = Q K^T ----
        ffrag sacc[2][4];
        #pragma unroll
        for (int rf = 0; rf < 2; rf++)
            #pragma unroll
            for (int ct = 0; ct < 4; ct++) sacc[rf][ct] = (ffrag)0.0f;
        #pragma unroll
        for (int ct = 0; ct < 4; ct++) {
            #pragma unroll
            for (int kc = 0; kc < 2; kc++) {
                const bfrag kb = *(const bfrag*)&Ks[ct * 16 + lcol][kc * 32 + quad * 8];
                sacc[0][ct] = __builtin_amdgcn_mfma_f32_16x16x32_bf16(qa[0][kc], kb, sacc[0][ct], 0, 0, 0);
                sacc[1][ct] = __builtin_amdgcn_mfma_f32_16x16x32_bf16(qa[1][kc], kb, sacc[1][ct], 0, 0, 0);
            }
        }

        // ---- scale + causal mask ----
        float s[2][4][4];
        #pragma unroll
        for (int rf = 0; rf < 2; rf++)
            #pragma unroll
            for (int ct = 0; ct < 4; ct++)
                #pragma unroll
                for (int r = 0; r < 4; r++) {
                    int qi = q0 + w * 32 + rf * 16 + quad * 4 + r;
                    int kj = j0 + ct * 16 + lcol;
                    s[rf][ct][r] = (kj <= qi) ? sacc[rf][ct][r] * 0.125f : -1e30f;
                }

        // ---- online softmax (DPP reductions on VALU pipe) ----
        float alpha[2][4];
        #pragma unroll
        for (int rf = 0; rf < 2; rf++)
            #pragma unroll
            for (int r = 0; r < 4; r++) {
                float mx = fmaxf(fmaxf(s[rf][0][r], s[rf][1][r]),
                                 fmaxf(s[rf][2][r], s[rf][3][r]));
                mx = rmax16(mx);
                float mnew = fmaxf(m_run[rf][r], mx);
                alpha[rf][r] = __expf(m_run[rf][r] - mnew);
                m_run[rf][r] = mnew;
                float rs = 0.0f;
                #pragma unroll
                for (int ct = 0; ct < 4; ct++) {
                    float p = __expf(s[rf][ct][r] - mnew);
                    s[rf][ct][r] = p;
                    rs += p;
                }
                rs = rsum16(rs);
                l_run[rf][r] = l_run[rf][r] * alpha[rf][r] + rs;
            }

        // ---- P: C-layout -> per-wave LDS -> A-layout ----
        #pragma unroll
        for (int rf = 0; rf < 2; rf++)
            #pragma unroll
            for (int ct = 0; ct < 4; ct++)
                #pragma unroll
                for (int r = 0; r < 4; r++)
                    Ps[w][rf * 16 + quad * 4 + r][ct * 16 + lcol] = f2bu(s[rf][ct][r]);

        #pragma unroll
        for (int rf = 0; rf < 2; rf++)
            #pragma unroll
            for (int ct = 0; ct < 4; ct++)
                #pragma unroll
                for (int r = 0; r < 4; r++)
                    oacc[rf][ct][r] *= alpha[rf][r];

        // ---- O += P V ----
        bfrag pa[2][2];
        #pragma unroll
        for (int rf = 0; rf < 2; rf++)
            #pragma unroll
            for (int kc = 0; kc < 2; kc++)
                pa[rf][kc] = *(const bfrag*)&Ps[w][rf * 16 + lcol][kc * 32 + quad * 8];
        #pragma unroll
        for (int ct = 0; ct < 4; ct++) {
            #pragma unroll
            for (int kc = 0; kc < 2; kc++) {
                const bfrag vb = *(const bfrag*)&Vs[ct * 16 + lcol][kc * 32 + quad * 8];
                oacc[0][ct] = __builtin_amdgcn_mfma_f32_16x16x32_bf16(pa[0][kc], vb, oacc[0][ct], 0, 0, 0);
                oacc[1][ct] = __builtin_amdgcn_mfma_f32_16x16x32_bf16(pa[1][kc], vb, oacc[1][ct], 0, 0, 0);
            }
        }
        __syncthreads();
    }

    // ---- store bf16 partials + (m,l) at logical slot ----
    const int slot = cidx * 16 + h;
    #pragma unroll
    for (int rf = 0; rf < 2; rf++)
        #pragma unroll
        for (int ct = 0; ct < 4; ct++)
            #pragma unroll
            for (int r = 0; r < 4; r++) {
                int ql = w * 32 + rf * 16 + quad * 4 + r;
                OpH[(size_t)slot * 8192 + ql * 64 + ct * 16 + lcol] = f2bu(oacc[rf][ct][r]);
            }
    if (lcol == 0) {
        #pragma unroll
        for (int rf = 0; rf < 2; rf++)
            #pragma unroll
            for (int r = 0; r < 4; r++) {
                int ql = w * 32 + rf * 16 + quad * 4 + r;
                ml2[(size_t)slot * 128 + ql] = make_float2(m_run[rf][r], l_run[rf][r]);
            }
    }
}

// ---------------- combine partials -> Om (bf16) ----------------
__global__ __launch_bounds__(256)
void attn_combine(const u16* __restrict__ OpH, const float2* __restrict__ ml2,
                  u16* __restrict__ Om) {
    const int row = blockIdx.x;       // 0..2047
    const int i = row >> 7;
    const int ql = row & 127;
    const int t = threadIdx.x;
    const int h = t >> 4;
    const int d = (t & 15) * 4;
    const int nc  = (i < 4) ? 1 : (i < 8) ? 2 : (i < 12) ? 3 : 4;
    const int pfx = (i < 4) ? i : (i < 8) ? 4 + 2 * (i - 4)
                  : (i < 12) ? 12 + 3 * (i - 8) : 24 + 4 * (i - 12);

    float M = -1e30f;
    for (int c = 0; c < nc; c++) {
        float2 m = ml2[(size_t)((pfx + c) * 16 + h) * 128 + ql];
        M = fmaxf(M, m.x);
    }
    float L = 0.0f;
    float acc[4] = {0.0f, 0.0f, 0.0f, 0.0f};
    for (int c = 0; c < nc; c++) {
        float2 m = ml2[(size_t)((pfx + c) * 16 + h) * 128 + ql];
        float wgt = __expf(m.x - M);
        L += m.y * wgt;
        size_t off = (size_t)((pfx + c) * 16 + h) * 8192 + ql * 64 + d;
        ushort4 v = *(const ushort4*)&OpH[off];
        acc[0] += b2f(v.x) * wgt; acc[1] += b2f(v.y) * wgt;
        acc[2] += b2f(v.z) * wgt; acc[3] += b2f(v.w) * wgt;
    }
    float inv = 1.0f / L;
    #pragma unroll
    for (int k = 0; k < 4; k++)
        Om[(size_t)row * D_MODEL + h * 64 + d + k] = f2bu(acc[k] * inv);
}

extern "C" void kernel_launch(void* const* d_in, const int* in_sizes, int n_in,
                              void* d_out, int out_size, void* d_ws, size_t ws_size,
                              hipStream_t stream) {
    const void* X  = d_in[0];
    const void* Wq = d_in[1];
    const void* Wk = d_in[2];
    const void* Wv = d_in[3];
    const void* Wo = d_in[4];
    float* out = (float*)d_out;            // fp32 output

    // d_out scratch: XrB bf16 (4MB), dead after qkv_mfma.
    u16* XrB = (u16*)d_out;

    // ws (>=32.1MB proven): mode 64B | Qm 4MB | Km 1MB | Vm 1MB | Om 4MB |
    //                       Vt 1MB | OpH 10.49MB | ml2 0.64MB  = 22.7MB
    int* mode = (int*)d_ws;
    u16* Qm = (u16*)((char*)d_ws + 64);
    u16* Km = Qm + (size_t)S_LEN * D_MODEL;
    u16* Vm = Km + (size_t)S_LEN * KV_DIM;
    u16* Om = Vm + (size_t)S_LEN * KV_DIM;
    u16* Vt = Om + (size_t)S_LEN * D_MODEL;
    u16* OpH = Vt + (size_t)KV_DIM * S_LEN;
    float2* ml2 = (float2*)(OpH + (size_t)640 * 8192);

    probe5_kernel<<<1, 64, 0, stream>>>(
        (const u16*)X, (const u16*)Wq, (const u16*)Wk, (const u16*)Wv,
        (const u16*)Wo, mode);

    rope_kernel<<<S_LEN, 512, 0, stream>>>(X, XrB, mode + 0);

    qkv_mfma<<<dim3((D_MODEL + 2 * KV_DIM) / 64, S_LEN / 128), 256, 0, stream>>>(
        XrB, Wq, Wk, Wv, Qm, Km, Vm, mode);

    vt_kernel<<<dim3(S_LEN / 64, KV_DIM / 64), 256, 0, stream>>>(Vm, Vt);

    attn_part<<<640, 256, 0, stream>>>(Qm, Km, Vt, OpH, ml2);

    attn_combine<<<S_LEN, 256, 0, stream>>>(OpH, ml2, Om);

    oproj_mfma<<<dim3(D_MODEL / 64, S_LEN / 128), 256, 0, stream>>>(Om, Wo, out, mode);
}